// Round 4
// baseline (662.705 us; speedup 1.0000x reference)
//
#include <hip/hip_runtime.h>

// segment_sum(h_t, batch, num_segments=10000)
//   h_t:   [N_NODES=1e6, FEAT=128] float32   (d_in[0])
//   batch: [N_NODES] int32, SORTED ascending (d_in[1])
//   out:   [10000, 128] float32              (d_out)
//
// batch sorted => contiguous runs (avg ~100 rows). Wave owns ROWS_PER_WAVE
// contiguous rows. Lane l handles cols [(l&31)*4 .. +3] of row r + (l>>5):
// one global_load_dwordx4 per lane covers TWO rows per wave. 16-row unroll
// => 8 data loads + 4 batch loads in flight. Per-lane predicated run-boundary
// flush via atomicAdd (rare).
//
// R1: per-row load->branch dep => ~0.7 TB/s.  R2: 8-deep dwordx2 => ~3.3.
// R3: dwordx4 (half the load instrs) => NEUTRAL vs R2 => shared plateau.
// R4 discriminator: drop nontemporal loads (shared by R2/R3; suspect they
// forgo L2 path benefits) + ROWS_PER_WAVE 128->64 (2x TLP oversubscription).

#define FEAT 128
#define ROWS_PER_WAVE 64  // 15625 waves -> ~15 blocks/CU queued (8 resident)

typedef float vfloat4 __attribute__((ext_vector_type(4)));

__global__ __launch_bounds__(256) void segsum_kernel(
    const float* __restrict__ h,
    const int* __restrict__ batch,
    float* __restrict__ out,
    int n_rows) {
  const int wave = (blockIdx.x * blockDim.x + threadIdx.x) >> 6;
  const int lane = threadIdx.x & 63;
  const int sub = lane >> 5;         // which row of the pair this lane covers
  const int col = (lane & 31) * 4;   // 4 consecutive floats (16B coalesced)

  long long row0 = (long long)wave * ROWS_PER_WAVE;
  if (row0 >= n_rows) return;
  long long row_end = row0 + ROWS_PER_WAVE;
  if (row_end > n_rows) row_end = n_rows;

  vfloat4 acc = {0.0f, 0.0f, 0.0f, 0.0f};
  long long first = row0 + sub;
  int cur = batch[first < n_rows ? first : (n_rows - 1)];

#define STEP(B, V)                                        \
  {                                                       \
    const int b_ = (B);                                   \
    if (b_ != cur) { /* per-lane, rarely taken */         \
      float* dst = out + (long long)cur * FEAT + col;     \
      atomicAdd(dst + 0, acc.x);                          \
      atomicAdd(dst + 1, acc.y);                          \
      atomicAdd(dst + 2, acc.z);                          \
      atomicAdd(dst + 3, acc.w);                          \
      acc.x = 0.0f; acc.y = 0.0f;                         \
      acc.z = 0.0f; acc.w = 0.0f;                         \
      cur = b_;                                           \
    }                                                     \
    acc.x += (V).x; acc.y += (V).y;                       \
    acc.z += (V).z; acc.w += (V).w;                       \
  }

  long long r = row0;
  // Main loop: 16 rows (8 pairs) per iteration; all loads issued before any
  // consume => 8 x dwordx4 (data) + 4 x dwordx4 (batch) outstanding.
  for (; r + 16 <= row_end; r += 16) {
    const int4 ba = *(const int4*)(batch + r);
    const int4 bb = *(const int4*)(batch + r + 4);
    const int4 bc = *(const int4*)(batch + r + 8);
    const int4 bd = *(const int4*)(batch + r + 12);
    const float* hp = h + (r + sub) * (long long)FEAT + col;
    vfloat4 v0 = *(const vfloat4*)(hp + 0 * 2 * FEAT);
    vfloat4 v1 = *(const vfloat4*)(hp + 1 * 2 * FEAT);
    vfloat4 v2 = *(const vfloat4*)(hp + 2 * 2 * FEAT);
    vfloat4 v3 = *(const vfloat4*)(hp + 3 * 2 * FEAT);
    vfloat4 v4 = *(const vfloat4*)(hp + 4 * 2 * FEAT);
    vfloat4 v5 = *(const vfloat4*)(hp + 5 * 2 * FEAT);
    vfloat4 v6 = *(const vfloat4*)(hp + 6 * 2 * FEAT);
    vfloat4 v7 = *(const vfloat4*)(hp + 7 * 2 * FEAT);

    STEP(sub ? ba.y : ba.x, v0)
    STEP(sub ? ba.w : ba.z, v1)
    STEP(sub ? bb.y : bb.x, v2)
    STEP(sub ? bb.w : bb.z, v3)
    STEP(sub ? bc.y : bc.x, v4)
    STEP(sub ? bc.w : bc.z, v5)
    STEP(sub ? bd.y : bd.x, v6)
    STEP(sub ? bd.w : bd.z, v7)
  }

  // Pair tail
  for (; r + 2 <= row_end; r += 2) {
    const int b = batch[r + sub];
    const vfloat4 v = *(const vfloat4*)(h + (r + sub) * (long long)FEAT + col);
    STEP(b, v)
  }
  // Odd last row (final chunk when n_rows is odd)
  if (r < row_end && sub == 0) {
    const int b = batch[r];
    const vfloat4 v = *(const vfloat4*)(h + r * (long long)FEAT + col);
    STEP(b, v)
  }
#undef STEP

  // Final flush (run may continue into the next wave's chunk)
  {
    float* dst = out + (long long)cur * FEAT + col;
    atomicAdd(dst + 0, acc.x);
    atomicAdd(dst + 1, acc.y);
    atomicAdd(dst + 2, acc.z);
    atomicAdd(dst + 3, acc.w);
  }
}

extern "C" void kernel_launch(void* const* d_in, const int* in_sizes, int n_in,
                              void* d_out, int out_size, void* d_ws, size_t ws_size,
                              hipStream_t stream) {
  const float* h_t = (const float*)d_in[0];
  const int* batch = (const int*)d_in[1];
  float* out = (float*)d_out;
  const int n_rows = in_sizes[1];  // N_NODES

  // d_out is poisoned with 0xAA before every launch — zero it first.
  hipMemsetAsync(d_out, 0, (size_t)out_size * sizeof(float), stream);

  const int n_waves = (n_rows + ROWS_PER_WAVE - 1) / ROWS_PER_WAVE;
  const int block = 256;  // 4 waves/block
  const int waves_per_block = block / 64;
  const int grid = (n_waves + waves_per_block - 1) / waves_per_block;

  segsum_kernel<<<grid, block, 0, stream>>>(h_t, batch, out, n_rows);
}